// Round 14
// baseline (647.363 us; speedup 1.0000x reference)
//
#include <hip/hip_runtime.h>
#include <hip/hip_bf16.h>
#include <stdint.h>

#define VOCAB 50000
#define EMB   128
#define HID   256
#define G4    1024   // 4*HID, gate order i,f,g,o
#define BATCH 256
#define SEQ   512
#define LOG2E 1.4426950408889634f

typedef __attribute__((ext_vector_type(8))) short bf16x8;
typedef __attribute__((ext_vector_type(4))) float f32x4;
typedef __attribute__((ext_vector_type(4))) int   i32x4;
typedef __attribute__((ext_vector_type(2))) unsigned u32x2;

__device__ __forceinline__ ushort f2bf(float f) {
  uint32_t u; __builtin_memcpy(&u, &f, 4);
  uint32_t r = (u + 0x7fffu + ((u >> 16) & 1u)) >> 16;  // RNE
  return (ushort)r;
}
__device__ __forceinline__ float asf(uint32_t x) {
  float f; __builtin_memcpy(&f, &x, 4);
  return f;
}
__device__ __forceinline__ float rcp(float x) { return __builtin_amdgcn_rcpf(x); }
__device__ __forceinline__ float ex2(float x) { return __builtin_amdgcn_exp2f(x); }

#define WAIT_LGKM() asm volatile("s_waitcnt lgkmcnt(0)" ::: "memory")
#define RAW_BAR()  do { __builtin_amdgcn_sched_barrier(0); \
                        __builtin_amdgcn_s_barrier(); \
                        __builtin_amdgcn_sched_barrier(0); } while (0)

// ---------------------------------------------------------------------------
// K1: proj_table[v][j*4+gate] = (emb[v]@W_ih + b_ih + b_hh) * LOG2E  (bf16,
// gate-interleaved, log2-prescaled). Unchanged (r8-r13).
// ---------------------------------------------------------------------------
__global__ __launch_bounds__(256) void k_proj(
    const float* __restrict__ emb, const float* __restrict__ W_ih,
    const float* __restrict__ b_ih, const float* __restrict__ b_hh,
    ushort* __restrict__ proj) {
  const int lane = threadIdx.x & 63;
  const int wv = threadIdx.x >> 6;
  const int vbase = (blockIdx.x * 4 + wv) * 64;
  const int lm = lane & 15, lq = lane >> 4;
  const int nt0 = blockIdx.y * 32;

  bf16x8 A[4][4];
  #pragma unroll
  for (int mt = 0; mt < 4; ++mt) {
    int v = vbase + mt * 16 + lm;
    int vc = v < VOCAB ? v : 0;
    const float* rp = emb + (size_t)vc * EMB;
    #pragma unroll
    for (int kt = 0; kt < 4; ++kt) {
      const float* p = rp + kt * 32 + lq * 8;
      #pragma unroll
      for (int i = 0; i < 8; ++i) A[mt][kt][i] = (short)f2bf(p[i]);
    }
  }
  for (int ntl = 0; ntl < 32; ++ntl) {
    const int g = (nt0 + ntl) * 16 + lm;             // gate-major row 0..1023
    const int newcol = (g & 255) * 4 + (g >> 8);     // j*4 + gate
    bf16x8 B[4];
    #pragma unroll
    for (int kt = 0; kt < 4; ++kt) {
      const float* p = W_ih + (size_t)g * EMB + kt * 32 + lq * 8;
      #pragma unroll
      for (int i = 0; i < 8; ++i) B[kt][i] = (short)f2bf(p[i]);
    }
    const float bias = b_ih[g] + b_hh[g];
    #pragma unroll
    for (int mt = 0; mt < 4; ++mt) {
      f32x4 acc = {0.f, 0.f, 0.f, 0.f};
      #pragma unroll
      for (int kt = 0; kt < 4; ++kt)
        acc = __builtin_amdgcn_mfma_f32_16x16x32_bf16(A[mt][kt], B[kt], acc, 0, 0, 0);
      #pragma unroll
      for (int r = 0; r < 4; ++r) {
        int row = vbase + mt * 16 + lq * 4 + r;
        if (row < VOCAB) proj[(size_t)row * G4 + newcol] = f2bf((acc[r] + bias) * LOG2E);
      }
    }
  }
}

// ---------------------------------------------------------------------------
// K2: MFMA-side weights: gates g,o (W_hh rows 512..1023) quantized to i8 and
// swizzled into mfma_i32_16x16x64_i8 B-frag order (r7-verified mapping).
// t in [0,8192): lane=t&63, kc=(t>>6)&3, nt2=(t>>8)&3, wv=(t>>10)&7.
// grow = 512 + (nt2>>1)*256 + wv*32 + (nt2&1)*16 + (lane&15);
// k0 = kc*64 + (lane>>4)*16.  16 bytes -> i32x4 at W2 + t*4.
// ---------------------------------------------------------------------------
__global__ __launch_bounds__(256) void k_w2(const float* __restrict__ Whh,
                                            int* __restrict__ W2) {
  const int t = blockIdx.x * 256 + threadIdx.x;      // 0..8191
  const int lane = t & 63, kc = (t >> 6) & 3, nt2 = (t >> 8) & 3, wv = (t >> 10) & 7;
  const int grow = 512 + (nt2 >> 1) * 256 + wv * 32 + (nt2 & 1) * 16 + (lane & 15);
  const int k0 = kc * 64 + (lane >> 4) * 16;
  const float* src = Whh + (size_t)grow * HID + k0;
  unsigned d[4];
  #pragma unroll
  for (int e = 0; e < 4; ++e) {
    unsigned acc = 0;
    #pragma unroll
    for (int b = 0; b < 4; ++b) {
      int q = (int)rintf(src[e * 4 + b] * 2032.f);
      q = q > 127 ? 127 : (q < -127 ? -127 : q);
      acc |= ((unsigned)q & 0xffu) << (8 * b);
    }
    d[e] = acc;
  }
  i32x4 o = {(int)d[0], (int)d[1], (int)d[2], (int)d[3]};
  *(i32x4*)(W2 + (size_t)t * 4) = o;
}

// ---------------------------------------------------------------------------
// K3w: dot4-side weights: gates i,f (W_hh rows 0..511), K-split-2 pack.
// t in [0,8192): lane=t&63, n=(t>>6)&15, wv=t>>10.  gate=n>>3, kk=n&7,
// jl=lane&31, kh=lane>>5.  grow = gate*256 + wv*32 + jl;
// k0 = kh*128 + kk*16.  16 bytes -> i32x4 at W3 + t*4.
// ---------------------------------------------------------------------------
__global__ __launch_bounds__(256) void k_w3(const float* __restrict__ Whh,
                                            int* __restrict__ W3) {
  const int t = blockIdx.x * 256 + threadIdx.x;      // 0..8191
  const int lane = t & 63, n = (t >> 6) & 15, wv = t >> 10;
  const int gate = n >> 3, kk = n & 7;
  const int grow = gate * 256 + wv * 32 + (lane & 31);
  const int k0 = (lane >> 5) * 128 + kk * 16;
  const float* src = Whh + (size_t)grow * HID + k0;
  unsigned d[4];
  #pragma unroll
  for (int e = 0; e < 4; ++e) {
    unsigned acc = 0;
    #pragma unroll
    for (int b = 0; b < 4; ++b) {
      int q = (int)rintf(src[e * 4 + b] * 2032.f);
      q = q > 127 ? 127 : (q < -127 ? -127 : q);
      acc |= ((unsigned)q & 0xffu) << (8 * b);
    }
    d[e] = acc;
  }
  i32x4 o = {(int)d[0], (int)d[1], (int)d[2], (int)d[3]};
  *(i32x4*)(W3 + (size_t)t * 4) = o;
}

// ---------------------------------------------------------------------------
// K4: hybrid-pipe LSTM — 256 blocks x 512 threads, ONE batch row per block.
// Gates g,o on the MATRIX pipe (16 MFMA/wave, weights in AGPRs — native);
// gates i,f on the VALU via dot4 K-split-2 (64 dot4/wave-lane, only 64 VGPR
// weights -> resident; K-combine = shfl_xor(32) add, no selects). The two
// pipes co-issue (m114). h: compact 256B LDS row, ping-pong.
// Lane: jl=lane&31 -> j=wv*32+jl; kh=lane>>5 (dot4 K-half);
// js=(lane>>4)&1, lm=lane&15 (MFMA extraction).
// ---------------------------------------------------------------------------
__global__ __launch_bounds__(512, 1) void k_lstm(
    const int* __restrict__ x, const ushort* __restrict__ proj,
    const int* __restrict__ W2, const int* __restrict__ W3,
    const float* __restrict__ W_fc, const float* __restrict__ b_fc,
    float* __restrict__ out) {
  __shared__ __align__(16) char hbuf[2][256];        // i8 h row, ping-pong
  __shared__ __align__(16) int xlds[SEQ];            // this row's token ids
  __shared__ float red[8];

  const int tid = threadIdx.x;
  const int lane = tid & 63, wv = tid >> 6;          // 8 waves
  const int jl = lane & 31, kh = lane >> 5;
  const int j = wv * 32 + jl;
  const int js = (lane >> 4) & 1, lm = lane & 15;
  const int lq = lane >> 4;                          // A-frag k-sub (0..3)
  const int b0 = blockIdx.x;
  const int bp = lm * 4;                             // bperm src: C row0 col lm
  const unsigned colb = (unsigned)j * 8u;            // proj byte off (4 gates)

  // --- MFMA weights (g,o): 16 frags = 64 regs, pinned in AGPRs ---
  i32x4 Wf[4][4];                                    // [nt2][kc]
  {
    const i32x4* wb = (const i32x4*)W2;
    #pragma unroll
    for (int nt2 = 0; nt2 < 4; ++nt2)
      #pragma unroll
      for (int kc = 0; kc < 4; ++kc)
        Wf[nt2][kc] = wb[((wv * 4 + nt2) * 4 + kc) * 64 + lane];
    #pragma unroll
    for (int nt2 = 0; nt2 < 4; ++nt2)
      #pragma unroll
      for (int kc = 0; kc < 4; ++kc)
        asm volatile("" : "+a"(Wf[nt2][kc]));
  }
  // --- dot4 weights (i,f): 16 dwordx4 = 64 VGPRs, pinned ---
  i32x4 Wd[16];                                      // n = gate*8 + kk
  {
    const i32x4* wb = (const i32x4*)W3;
    #pragma unroll
    for (int n = 0; n < 16; ++n)
      Wd[n] = wb[(wv * 16 + n) * 64 + lane];
    #pragma unroll
    for (int n = 0; n < 16; ++n)
      asm volatile("" : "+v"(Wd[n]));
  }

  for (int i = tid; i < SEQ; i += 512) xlds[i] = x[b0 * SEQ + i];
  if (tid < 128) ((int*)hbuf)[tid] = 0;

  float c = 0.f, hl = 0.f;
  __syncthreads();

  const char* projb = (const char*)proj;
  u32x2 xp0, xp1;                                    // 2-step prefetch
  xp0 = *(const u32x2*)(projb + (unsigned)xlds[0] * 2048u + colb);
  xp1 = *(const u32x2*)(projb + (unsigned)xlds[1] * 2048u + colb);

  const float S2 = LOG2E / 258064.f;                 // 2032*127 dequant, log2

#define STEP(T, RB, WB, XP)                                                   \
  {                                                                           \
    const char* hb_ = hbuf[RB];                                               \
    i32x4 A[4];                                      /* MFMA A-frags */       \
    _Pragma("unroll")                                                         \
    for (int kc = 0; kc < 4; ++kc)                                            \
      A[kc] = *(const i32x4*)(hb_ + kc * 64 + lq * 16);                       \
    i32x4 hq[8];                                     /* dot4 h K-half */      \
    _Pragma("unroll")                                                         \
    for (int kk = 0; kk < 8; ++kk)                                            \
      hq[kk] = *(const i32x4*)(hb_ + kh * 128 + kk * 16);                     \
    /* matrix pipe: gates g,o (4 tiles x 4 kc) */                             \
    i32x4 ag0 = {0,0,0,0}, ag1 = {0,0,0,0}, ao0 = {0,0,0,0}, ao1 = {0,0,0,0}; \
    _Pragma("unroll")                                                         \
    for (int kc = 0; kc < 4; ++kc) {                                          \
      ag0 = __builtin_amdgcn_mfma_i32_16x16x64_i8(A[kc], Wf[0][kc], ag0, 0, 0, 0); \
      ag1 = __builtin_amdgcn_mfma_i32_16x16x64_i8(A[kc], Wf[1][kc], ag1, 0, 0, 0); \
      ao0 = __builtin_amdgcn_mfma_i32_16x16x64_i8(A[kc], Wf[2][kc], ao0, 0, 0, 0); \
      ao1 = __builtin_amdgcn_mfma_i32_16x16x64_i8(A[kc], Wf[3][kc], ao1, 0, 0, 0); \
    }                                                                         \
    /* VALU pipe: gates i,f (half-K each lane), 2 chains per gate */          \
    int pi0 = 0, pi1 = 0, pf0 = 0, pf1 = 0;                                   \
    _Pragma("unroll")                                                         \
    for (int kk = 0; kk < 8; ++kk) {                                          \
      _Pragma("unroll")                                                       \
      for (int e = 0; e < 4; ++e) {                                           \
        if (kk & 1) {                                                         \
          pi1 = __builtin_amdgcn_sdot4(hq[kk][e], Wd[kk][e], pi1, false);     \
          pf1 = __builtin_amdgcn_sdot4(hq[kk][e], Wd[8 + kk][e], pf1, false); \
        } else {                                                              \
          pi0 = __builtin_amdgcn_sdot4(hq[kk][e], Wd[kk][e], pi0, false);     \
          pf0 = __builtin_amdgcn_sdot4(hq[kk][e], Wd[8 + kk][e], pf0, false); \
        }                                                                     \
      }                                                                       \
    }                                                                         \
    int ai = pi0 + pi1; ai += __shfl_xor(ai, 32);    /* K-combine */          \
    int af = pf0 + pf1; af += __shfl_xor(af, 32);                             \
    /* extract g,o from MFMA C row 0 (lanes 0-15, reg 0) */                   \
    int g0 = __builtin_amdgcn_ds_bpermute(bp, ag0[0]);                        \
    int g1 = __builtin_amdgcn_ds_bpermute(bp, ag1[0]);                        \
    int o0 = __builtin_amdgcn_ds_bpermute(bp, ao0[0]);                        \
    int o1 = __builtin_amdgcn_ds_bpermute(bp, ao1[0]);                        \
    int agv = js ? g1 : g0;                                                   \
    int aov = js ? o1 : o0;                                                   \
    float gi = (float)ai * S2 + asf(XP[0] << 16);                             \
    float gf = (float)af * S2 + asf(XP[0] & 0xffff0000u);                     \
    float gg = (float)agv * S2 + asf(XP[1] << 16);                            \
    float go = (float)aov * S2 + asf(XP[1] & 0xffff0000u);                    \
    float si_ = rcp(1.f + ex2(-gi));                                          \
    float sf_ = rcp(1.f + ex2(-gf));                                          \
    float eg_ = ex2(gg + gg);                                                 \
    float tg_ = (eg_ - 1.f) * rcp(eg_ + 1.f);                                 \
    float so_ = rcp(1.f + ex2(-go));                                          \
    float cn_ = sf_ * c + si_ * tg_;                                          \
    c = cn_;                                                                  \
    float e2_ = ex2(cn_ * (2.f * LOG2E));                                     \
    float tc_ = 1.f - 2.f * rcp(e2_ + 1.f);                                   \
    float h_ = so_ * tc_;                                                     \
    hl = h_;                                                                  \
    if (kh == 0) hbuf[WB][j] = (char)(int)rintf(h_ * 127.f);                  \
    {                                                /* gather t+2 */         \
      int t2_ = ((T) + 2 < SEQ) ? (T) + 2 : SEQ - 1;                          \
      XP = *(const u32x2*)(projb + (unsigned)xlds[t2_] * 2048u + colb);       \
    }                                                                         \
    WAIT_LGKM();                                                              \
    RAW_BAR();                                                                \
  }

  STEP(0, 0, 1, xp0);                                // t=0 (h=0 -> mm terms 0)
  #pragma clang loop unroll(disable)
  for (int tt = 0; tt < 255; ++tt) {                 // t = 1..510 in pairs
    STEP(2 * tt + 1, 1, 0, xp1);
    STEP(2 * tt + 2, 0, 1, xp0);
  }
  STEP(511, 1, 0, xp1);                              // final step

  // --- FC + sigmoid epilogue (all lanes hold hl for their j) ---
  float p = hl * W_fc[j];
  p += __shfl_xor(p, 1);
  p += __shfl_xor(p, 2);
  p += __shfl_xor(p, 4);
  p += __shfl_xor(p, 8);
  p += __shfl_xor(p, 16);          // sum over the wave's 32 j (per K-half)
  if (lane == 0) red[wv] = p;
  __syncthreads();
  if (tid == 0) {
    float s = 0.f;
    #pragma unroll
    for (int w = 0; w < 8; ++w) s += red[w];
    s += b_fc[0];
    out[b0] = rcp(1.f + ex2(-s * LOG2E));
  }
}

// ---------------------------------------------------------------------------
extern "C" void kernel_launch(void* const* d_in, const int* in_sizes, int n_in,
                              void* d_out, int out_size, void* d_ws, size_t ws_size,
                              hipStream_t stream) {
  const int*   x    = (const int*)d_in[0];
  const float* emb  = (const float*)d_in[1];
  const float* W_ih = (const float*)d_in[2];
  const float* W_hh = (const float*)d_in[3];
  const float* b_ih = (const float*)d_in[4];
  const float* b_hh = (const float*)d_in[5];
  const float* W_fc = (const float*)d_in[6];
  const float* b_fc = (const float*)d_in[7];
  float* out = (float*)d_out;

  // ws: proj 102,400,000 B | W2 (g,o MFMA frags) 131,072 B | W3 (i,f dot4) 131,072 B
  char* ws = (char*)d_ws;
  ushort* proj = (ushort*)ws;
  int*    W2   = (int*)(ws + 102400000);
  int*    W3   = (int*)(ws + 102531072);

  k_proj<<<dim3(196, 2), dim3(256), 0, stream>>>(emb, W_ih, b_ih, b_hh, proj);
  k_w2<<<dim3(32), dim3(256), 0, stream>>>(W_hh, W2);
  k_w3<<<dim3(32), dim3(256), 0, stream>>>(W_hh, W3);
  k_lstm<<<dim3(256), dim3(512), 0, stream>>>(x, proj, W2, W3, W_fc, b_fc, out);
}